// Round 3
// baseline (347.024 us; speedup 1.0000x reference)
//
#include <hip/hip_runtime.h>
#include <hip/hip_bf16.h>
#include <math.h>

typedef int   v4i __attribute__((ext_vector_type(4)));
typedef float v4f __attribute__((ext_vector_type(4)));

#define B_DIM   256
#define IN_DIM  1024
#define H4      4096
#define XELEM   (B_DIM * IN_DIM)         // 262144

// ---- ws layout (byte-identical footprint to round 2: total 9699392) ----
// [0,16)    maxm (4 floats)
// [64, +256KB) thresh double[2][4][4096]
// [+, +1MB) X planes int8[4][256][1024]
// [+, +8MB) cmp bytes [2][4][256][4096]   (also aliased early as k_max partials)
#define WS_THRESH_OFF 64
#define WS_X_OFF      (64 + 262144)
#define WS_CMP_OFF    (64 + 262144 + 1048576)

#define BAR()   __asm__ volatile("s_barrier" ::: "memory")
#define BARL()  __asm__ volatile("s_waitcnt lgkmcnt(0)\n\ts_barrier" ::: "memory")
#define WVM(n)  __asm__ volatile("s_waitcnt vmcnt(" #n ")" ::: "memory")

// ---------------- Pass A1: per-block maxes (NO atomics) ----------------
__global__ void k_max(const float* __restrict__ wih, const float* __restrict__ whh,
                      const float* __restrict__ bih, const float* __restrict__ bhh,
                      float* __restrict__ part) {
  int b = blockIdx.x, t = threadIdx.x;
  const v4f* p; size_t base; int iters;
  if (b < 512)       { p = (const v4f*)wih; base = (size_t)b * 8192;         iters = 32; }
  else if (b < 1024) { p = (const v4f*)whh; base = (size_t)(b - 512) * 8192; iters = 32; }
  else if (b == 1024){ p = (const v4f*)bih; base = 0;                         iters = 16; }
  else               { p = (const v4f*)bhh; base = 0;                         iters = 16; }
  float m = -3.4e38f;
#pragma unroll 4
  for (int it = 0; it < iters; ++it) {
    v4f v = p[base + (size_t)it * 256 + t];
    m = fmaxf(m, fmaxf(fmaxf(v.x, v.y), fmaxf(v.z, v.w)));
  }
#pragma unroll
  for (int off = 32; off >= 1; off >>= 1) m = fmaxf(m, __shfl_down(m, off, 64));
  __shared__ float sm[4];
  int w = t >> 6, ln = t & 63;
  if (ln == 0) sm[w] = m;
  __syncthreads();
  if (t == 0) part[b] = fmaxf(fmaxf(sm[0], sm[1]), fmaxf(sm[2], sm[3]));
}

// ---------------- Pass A1b: reduce partials (1 block) ----------------
__global__ void k_max2(const float* __restrict__ part, float* __restrict__ maxm) {
  int t = threadIdx.x;  // 256
  __shared__ float sm[4];
#pragma unroll
  for (int slot = 0; slot < 2; ++slot) {
    float m = fmaxf(part[slot * 512 + t], part[slot * 512 + 256 + t]);
#pragma unroll
    for (int off = 32; off >= 1; off >>= 1) m = fmaxf(m, __shfl_down(m, off, 64));
    int w = t >> 6, ln = t & 63;
    if (ln == 0) sm[w] = m;
    __syncthreads();
    if (t == 0) maxm[slot] = fmaxf(fmaxf(sm[0], sm[1]), fmaxf(sm[2], sm[3]));
    __syncthreads();
  }
  if (t == 0) { maxm[2] = part[1024]; maxm[3] = part[1025]; }
}

// ---------------- Pass A2: input bit-planes + bias thresholds ----------------
__global__ void k_prep(const float* __restrict__ input,
                       const float* __restrict__ bih, const float* __restrict__ bhh,
                       const float* __restrict__ ebih, const float* __restrict__ ebhh,
                       const float* __restrict__ a1p, const float* __restrict__ maxm,
                       double* __restrict__ thresh, signed char* __restrict__ X) {
  int gid = blockIdx.x * 256 + threadIdx.x;
  if (blockIdx.x < 1024) {                       // X part: 262144 elements
    float a1 = a1p[0];
    float x = input[gid];
    float t = fabsf(x), u = fabsf(t - a1);
    float sg = (x > 0.f) ? 0.5f : ((x < 0.f) ? -0.5f : 0.f);
    float p = sg * ((t - u) + a1);
    float inp01 = (p + a1) / (a1 * 2.0f);
    float q = rintf(15.0f * inp01);
    int qi = (int)q;
#pragma unroll
    for (int pl = 0; pl < 4; ++pl)
      X[pl * XELEM + gid] = (signed char)((qi >> (3 - pl)) & 1);
  } else {                                       // thresh part: 32768 elements
    int i2 = gid - 262144;                       // s*16384 + n*4096 + col
    int s = i2 >> 14; int r = i2 & 16383;
    const float* bp = s ? bhh : bih;
    const float* ep = s ? ebhh : ebih;
    float mb = maxm[2 + s];
    float bv = bp[r], ev = ep[r];
    float xc = fminf(fmaxf(bv, -0.9921875f), 0.9921875f);
    float qv = rintf(xc * 128.f) * 0.0078125f;
    float noise = (ev * mb) * 0.1f;
    float beff = bv + ((qv - bv) + noise);
    thresh[i2] = 0.5 - (double)beff;
  }
}

// ---------------- Pass B: exact digit-GEMM, LDS-DMA pipelined ----------------
// grid: x = ntile (128 tiles of 32 cols), y = sp (s*4+plane). block: 512 = 8 waves.
// K-loop: global_load_lds raw W/E (3 bufs, depth-2), fine vmcnt, raw s_barrier.
__global__ __launch_bounds__(512, 4) void k_gemm(
    const float* __restrict__ Wih, const float* __restrict__ Whh,
    const float* __restrict__ Eih, const float* __restrict__ Ehh,
    const float* __restrict__ maxm, const double* __restrict__ thresh,
    const signed char* __restrict__ X, unsigned char* __restrict__ cmp) {
  const int ntile = blockIdx.x;
  const int sp = blockIdx.y;
  const int s = sp >> 2, plane = sp & 3;
  const float* W = s ? Whh : Wih;
  const float* E = s ? Ehh : Eih;
  const float maxw = maxm[s];

  const int tid = threadIdx.x;
  const int wave = tid >> 6, lane = tid & 63, quad = lane >> 4, l15 = lane & 15;

  // raw staging: [buf][ W: 64 rows x 32 floats | E: same at +2048 ]
  __shared__ __align__(16) float raw[3][4096];
  // digitized weights: [buf][digit][n(32)][k(64, pad 80B)]
  __shared__ __align__(16) signed char dbuf[2][4][32][80];

  v4i acc[4][2][2];
#pragma unroll
  for (int d = 0; d < 4; ++d)
#pragma unroll
    for (int m = 0; m < 2; ++m)
#pragma unroll
      for (int n = 0; n < 2; ++n) acc[d][m][n] = (v4i){0, 0, 0, 0};

  // DMA source mapping: wave w, lane l -> row w*8 + l/8, float-col (l%8)*4
  const int dr = wave * 8 + (lane >> 3);
  const int dc = (lane & 7) * 4;
  const size_t tbase = (size_t)plane * (IN_DIM * H4) + (size_t)ntile * 32;
  const float* gW = W + tbase + (size_t)dr * H4 + dc;
  const float* gE = E + tbase + (size_t)dr * H4 + dc;

  const signed char* Xp = X + plane * XELEM;
  const int arow0 = wave * 32 + l15;

  // issue async raw-chunk DMA (vmcnt-tracked, zero VGPR result)
  auto dma = [&](int ch) {
    const int rb = ch % 3;
    const float* gw = gW + (size_t)(ch * 64) * H4;
    const float* ge = gE + (size_t)(ch * 64) * H4;
    __builtin_amdgcn_global_load_lds((const unsigned int*)gw,
                                     (unsigned int*)&raw[rb][wave * 256], 16, 0, 0);
    __builtin_amdgcn_global_load_lds((const unsigned int*)ge,
                                     (unsigned int*)&raw[rb][2048 + wave * 256], 16, 0, 0);
  };

  // digitize chunk from raw LDS -> dbuf (exact f32 chain; LDS round-trip bit-exact)
  const int sn = tid & 31, skq = tid >> 5;
  auto digitize = [&](int ch) {
    const int rb = ch % 3, db = ch & 1;
    int pk[4] = {0, 0, 0, 0};
#pragma unroll
    for (int j = 0; j < 4; ++j) {
      float w  = raw[rb][(skq * 4 + j) * 32 + sn];
      float ev = raw[rb][2048 + (skq * 4 + j) * 32 + sn];
      float xc = fminf(fmaxf(w, -0.9921875f), 0.9921875f);
      float qv = rintf(xc * 128.f) * 0.0078125f;
      float noise = (ev * maxw) * 0.1f;
      float a = w + ((qv - w) + noise);          // == w_eff, exact jax f32 chain
      float x0 = a * 8.f;    float f0 = rintf(x0); float r0 = x0 - f0;
      float x1 = r0 * 128.f; float f1 = rintf(x1); float r1 = x1 - f1;
      float x2 = r1 * 128.f; float f2 = rintf(x2); float r2 = x2 - f2;
      float x3 = r2 * 128.f; float f3 = rintf(x3);
      pk[0] |= ((int)f0 & 0xff) << (8 * j);
      pk[1] |= ((int)f1 & 0xff) << (8 * j);
      pk[2] |= ((int)f2 & 0xff) << (8 * j);
      pk[3] |= ((int)f3 & 0xff) << (8 * j);
    }
#pragma unroll
    for (int d = 0; d < 4; ++d)
      *(int*)&dbuf[db][d][sn][skq * 4] = pk[d];
  };

  auto loadA = [&](int ch, v4i a[2]) {
    a[0] = *(const v4i*)(Xp + (size_t)(arow0)      * IN_DIM + ch * 64 + quad * 16);
    a[1] = *(const v4i*)(Xp + (size_t)(arow0 + 16) * IN_DIM + ch * 64 + quad * 16);
  };

  auto mma = [&](int ch, const v4i a[2]) {
    const int db = ch & 1;
#pragma unroll
    for (int d = 0; d < 4; ++d)
#pragma unroll
      for (int ns = 0; ns < 2; ++ns) {
        v4i bfr = *(const v4i*)&dbuf[db][d][ns * 16 + l15][quad * 16];
        acc[d][0][ns] = __builtin_amdgcn_mfma_i32_16x16x64_i8(a[0], bfr, acc[d][0][ns], 0, 0, 0);
        acc[d][1][ns] = __builtin_amdgcn_mfma_i32_16x16x64_i8(a[1], bfr, acc[d][1][ns], 0, 0, 0);
      }
  };

  // ---- prologue: order = lds(0), A(0), lds(1)  (matches steady-state counting)
  v4i aCur[2], aNxt[2];
  dma(0);
  loadA(0, aCur);
  dma(1);

#pragma unroll
  for (int ch = 0; ch < 16; ++ch) {
    if (ch < 15) loadA(ch + 1, aNxt);     // A(ch+1): plain loads, 1-iter cover (L2-hot)
    if (ch < 14) dma(ch + 2);             // lds(ch+2): depth-2 async
    // wait ONLY for chunk ch's raw DMA; keep A(ch), lds(ch+1), A(ch+1), lds(ch+2) in flight
    if (ch < 14)       WVM(8);
    else if (ch == 14) WVM(6);
    else               WVM(2);
    BAR();                                 // raw[ch%3] visible to all waves (no vmcnt drain)
    digitize(ch);
    BARL();                                // digits visible (lgkm only, no vmcnt drain)
    mma(ch, aCur);
    aCur[0] = aNxt[0]; aCur[1] = aNxt[1];  // fully unrolled -> pure renaming
  }

  // ---- epilogue: exact combine + compare ----
  const double inv = 1.0 / 16777216.0;   // /(8*128^3)
  const double* thp = thresh + (size_t)sp * H4;
  unsigned char* cp = cmp + (size_t)sp * B_DIM * H4;
#pragma unroll
  for (int ms = 0; ms < 2; ++ms) {
#pragma unroll
    for (int ns = 0; ns < 2; ++ns) {
      int col = ntile * 32 + ns * 16 + l15;
      double th = thp[col];
#pragma unroll
      for (int r = 0; r < 4; ++r) {
        long long T = ((long long)acc[0][ms][ns][r] << 21) + ((long long)acc[1][ms][ns][r] << 14)
                    + ((long long)acc[2][ms][ns][r] << 7)  +  (long long)acc[3][ms][ns][r];
        int row = wave * 32 + ms * 16 + quad * 4 + r;
        cp[(size_t)row * H4 + col] = ((double)T * inv > th) ? 1 : 0;
      }
    }
  }
}

// ---------------- Pass C: pointwise LSTM ----------------
__device__ __forceinline__ float pact_(float x, float a) {
  float t = fabsf(x), u = fabsf(t - a);
  float sg = (x > 0.f) ? 0.5f : ((x < 0.f) ? -0.5f : 0.f);
  return sg * ((t - u) + a);
}
__device__ __forceinline__ float quant_(float x, float a) {
  float xr = x / a;
  xr = fminf(fmaxf(xr, -0.9921875f), 0.9921875f);
  return rintf(xr * 128.f) * 0.0078125f * a;
}
__device__ __forceinline__ float sigm_(float x) { return 1.0f / (1.0f + expf(-x)); }

__global__ void k_pointwise(const unsigned char* __restrict__ cmp, const float* __restrict__ cx,
                            const float* a3, const float* a4, const float* a5, const float* a6,
                            const float* a7, const float* a8, const float* a9, const float* a10,
                            const float* a11, float* __restrict__ out) {
  int idx = blockIdx.x * 256 + threadIdx.x;   // 0..262143
  int b = idx >> 10, h = idx & 1023;
  float g[4];
#pragma unroll
  for (int gi = 0; gi < 4; ++gi) {
    int col = gi * 1024 + h;
    float acc = 0.f;
#pragma unroll
    for (int n = 0; n < 4; ++n) {
      int o = (int)cmp[((size_t)(0 * 4 + n) * B_DIM + b) * H4 + col]
            + (int)cmp[((size_t)(1 * 4 + n) * B_DIM + b) * H4 + col];
      float beta = (float)(8 >> n) / 15.0f;
      acc = acc + beta * (float)o;
    }
    g[gi] = acc;
  }
  float fg = quant_(pact_(sigm_(g[2]), a3[0]), a3[0]);
  float ig = quant_(pact_(sigm_(g[0]), a4[0]), a4[0]);
  float ac = quant_(pact_(tanhf(g[1]), a5[0]), a5[0]);
  float og = quant_(pact_(sigm_(g[3]), a6[0]), a6[0]);
  float cxv = cx[idx];
  float gc = quant_(pact_(cxv * fg, a7[0]), a7[0]);
  float ai = quant_(pact_(ig * ac, a8[0]), a8[0]);
  float nc = quant_(pact_(gc + ai, a9[0]), a9[0]);
  float acl = quant_(pact_(tanhf(nc), a10[0]), a10[0]);
  float nh = quant_(pact_(acl * og, a11[0]), a11[0]);
  out[idx] = nh;
  out[XELEM + idx] = nc;
}

extern "C" void kernel_launch(void* const* d_in, const int* in_sizes, int n_in,
                              void* d_out, int out_size, void* d_ws, size_t ws_size,
                              hipStream_t stream) {
  (void)in_sizes; (void)n_in; (void)out_size; (void)ws_size;
  const float* input = (const float*)d_in[0];
  const float* cx    = (const float*)d_in[2];
  const float* wih   = (const float*)d_in[3];
  const float* whh   = (const float*)d_in[4];
  const float* bih   = (const float*)d_in[5];
  const float* bhh   = (const float*)d_in[6];
  const float* ewih  = (const float*)d_in[7];
  const float* ewhh  = (const float*)d_in[8];
  const float* ebih  = (const float*)d_in[9];
  const float* ebhh  = (const float*)d_in[10];
  const float* a1    = (const float*)d_in[11];
  const float* a3    = (const float*)d_in[12];
  const float* a4    = (const float*)d_in[13];
  const float* a5    = (const float*)d_in[14];
  const float* a6    = (const float*)d_in[15];
  const float* a7    = (const float*)d_in[16];
  const float* a8    = (const float*)d_in[17];
  const float* a9    = (const float*)d_in[18];
  const float* a10   = (const float*)d_in[19];
  const float* a11   = (const float*)d_in[20];
  float* out = (float*)d_out;

  char* ws = (char*)d_ws;
  float*         maxm   = (float*)ws;
  double*        thresh = (double*)(ws + WS_THRESH_OFF);
  signed char*   X      = (signed char*)(ws + WS_X_OFF);
  unsigned char* cmp    = (unsigned char*)(ws + WS_CMP_OFF);
  float*         part   = (float*)(ws + WS_CMP_OFF);  // aliases cmp: used only before k_gemm

  k_max<<<1026, 256, 0, stream>>>(wih, whh, bih, bhh, part);
  k_max2<<<1, 256, 0, stream>>>(part, maxm);
  k_prep<<<1152, 256, 0, stream>>>(input, bih, bhh, ebih, ebhh, a1, maxm, thresh, X);
  k_gemm<<<dim3(128, 8), 512, 0, stream>>>(wih, whh, ewih, ewhh, maxm, thresh, X, cmp);
  k_pointwise<<<1024, 256, 0, stream>>>(cmp, cx, a3, a4, a5, a6, a7, a8, a9, a10, a11, out);
}